// Round 7
// baseline (661.498 us; speedup 1.0000x reference)
//
#include <hip/hip_runtime.h>

typedef short short8 __attribute__((ext_vector_type(8)));
typedef float f32x4 __attribute__((ext_vector_type(4)));
typedef int i32x4 __attribute__((ext_vector_type(4)));

#define BATCH 32
#define DIM 192
#define RES 64
#define HW 4096
#define NH 4
#define DH 48
#define NWIN 16
#define LTOK 256
#define BUFE (BATCH * DIM * HW)  // 25,165,824 elems per bf16 buffer
#define SCALE_Q 0.14433756729740643f
#define LOG2E 1.4426950408889634f

__device__ __forceinline__ unsigned short f2bf(float f) {
  unsigned int u = __builtin_bit_cast(unsigned int, f);
  u += 0x7fffu + ((u >> 16) & 1u);
  return (unsigned short)(u >> 16);
}
__device__ __forceinline__ float bf2f(unsigned short h) {
  unsigned int u = ((unsigned int)h) << 16;
  return __builtin_bit_cast(float, u);
}
__device__ __forceinline__ f32x4 mfma16(short8 a, short8 b, f32x4 c) {
  return __builtin_amdgcn_mfma_f32_16x16x32_bf16(a, b, c, 0, 0, 0);
}

// ---------------------------------------------------------------------------
// K0: one-shot weight fp32->bf16 conversion into wbf[576][192] (lives in buf3,
// which is dead until k3 writes qf_w there).
// ---------------------------------------------------------------------------
__global__ __launch_bounds__(256) void k0_wcvt(
    const float* __restrict__ w_qk, const float* __restrict__ w_v,
    unsigned short* __restrict__ wbf) {
  int u = blockIdx.x * 256 + threadIdx.x;  // 0..27647
  int i4 = u * 4;
  const float* src = (i4 < 2 * DIM * DIM) ? (w_qk + i4) : (w_v + (i4 - 2 * DIM * DIM));
  float4 f = *(const float4*)src;
  uint2 pk;
  pk.x = (unsigned int)f2bf(f.x) | ((unsigned int)f2bf(f.y) << 16);
  pk.y = (unsigned int)f2bf(f.z) | ((unsigned int)f2bf(f.w) << 16);
  *(uint2*)&wbf[i4] = pk;
}

// ---------------------------------------------------------------------------
// K1: 1x1 convs as bf16 MFMA GEMM (unchanged from r4: short-lived staging
// regs, LDS-staged full-line output stores).
// ---------------------------------------------------------------------------
__global__ __launch_bounds__(256, 2) void k1_conv1x1(
    const float* __restrict__ x, const unsigned short* __restrict__ wbf,
    const float* __restrict__ b_qk, const float* __restrict__ b_v,
    unsigned short* __restrict__ q_raw, unsigned short* __restrict__ k_raw,
    unsigned short* __restrict__ v_buf) {
  __shared__ unsigned short Al[96 * 200];  // weight tile, stride 200
  __shared__ unsigned short Bl[64 * 200];  // x tile [px][ic], stride 200
  __shared__ unsigned short Os[96 * 68];   // output tile [oc][px], stride 68
  const int tid = threadIdx.x;
  const int pix0 = blockIdx.x * 64;
  const int b = blockIdx.y;

  // stage B (x tile) once: [px][ic] stride 200
  {
    const float* xb = x + (size_t)b * (DIM * HW) + pix0;
    int px = tid & 63;
    int icq = tid >> 6;
    for (int it = 0; it < 6; ++it) {
      int ic8 = icq + it * 4;
      const float* p = xb + (size_t)(ic8 * 8) * HW + px;
      unsigned short h[8];
#pragma unroll
      for (int j = 0; j < 8; ++j) h[j] = f2bf(p[(size_t)j * HW]);
      uint4 pk;
      pk.x = h[0] | ((unsigned int)h[1] << 16);
      pk.y = h[2] | ((unsigned int)h[3] << 16);
      pk.z = h[4] | ((unsigned int)h[5] << 16);
      pk.w = h[6] | ((unsigned int)h[7] << 16);
      *(uint4*)&Bl[px * 200 + ic8 * 8] = pk;
    }
  }

  const int lane = tid & 63, wv = tid >> 6;
  const int quad = lane >> 4, col = lane & 15;
  const int m0 = (wv >> 1) * 48, n0 = (wv & 1) * 32;

  for (int t = 0; t < 6; ++t) {
    // stage weight tile t: global(L2-resident) -> LDS, short-lived regs only
    {
      const unsigned short* wsrc = wbf + t * (96 * 192);
      uint4 tmp[9];
#pragma unroll
      for (int it = 0; it < 9; ++it) {
        int row = (it * 256 + tid) / 24, part = (it * 256 + tid) % 24;
        tmp[it] = *(const uint4*)(wsrc + row * 192 + part * 8);
      }
#pragma unroll
      for (int it = 0; it < 9; ++it) {
        int row = (it * 256 + tid) / 24, part = (it * 256 + tid) % 24;
        *(uint4*)&Al[row * 200 + part * 8] = tmp[it];
      }
    }
    __syncthreads();  // Al ready (t=0 also covers Bl staging)

    f32x4 acc[3][2];
#pragma unroll
    for (int fm = 0; fm < 3; ++fm)
#pragma unroll
      for (int fn = 0; fn < 2; ++fn) {
        acc[fm][fn][0] = 0.f; acc[fm][fn][1] = 0.f;
        acc[fm][fn][2] = 0.f; acc[fm][fn][3] = 0.f;
      }

#pragma unroll
    for (int ks = 0; ks < 6; ++ks) {
      short8 a[3], bb[2];
#pragma unroll
      for (int fm = 0; fm < 3; ++fm)
        a[fm] = *(const short8*)&Al[(m0 + fm * 16 + col) * 200 + ks * 32 + quad * 8];
#pragma unroll
      for (int fn = 0; fn < 2; ++fn)
        bb[fn] = *(const short8*)&Bl[(n0 + fn * 16 + col) * 200 + ks * 32 + quad * 8];
#pragma unroll
      for (int fm = 0; fm < 3; ++fm)
#pragma unroll
        for (int fn = 0; fn < 2; ++fn) acc[fm][fn] = mfma16(a[fm], bb[fn], acc[fm][fn]);
    }

    // write O tile (bias added, bf16) into Os [96 rows][stride 68]
    const int oc0 = t * 96;
#pragma unroll
    for (int fm = 0; fm < 3; ++fm) {
#pragma unroll
      for (int r = 0; r < 4; ++r) {
        int ocoff = m0 + fm * 16 + quad * 4 + r;
        int ocg = oc0 + ocoff;
        float bias = (ocg < 384) ? b_qk[ocg] : b_v[ocg - 384];
#pragma unroll
        for (int fn = 0; fn < 2; ++fn) {
          int px = n0 + fn * 16 + col;
          Os[ocoff * 68 + px] = f2bf(acc[fm][fn][r] + bias);
        }
      }
    }
    __syncthreads();  // Os ready; doubles as "all Al reads done" fence

    // cooperative full-line store: 8 lanes = one 128-B row line
    unsigned short* dst;
    int ocbase;
    if (oc0 < 192) { dst = q_raw; ocbase = oc0; }
    else if (oc0 < 384) { dst = k_raw; ocbase = oc0 - 192; }
    else { dst = v_buf; ocbase = oc0 - 384; }
    {
      int row0 = tid >> 3, part = tid & 7;
#pragma unroll
      for (int it = 0; it < 3; ++it) {
        int row = it * 32 + row0;
        *(uint4*)&dst[((size_t)b * DIM + (ocbase + row)) * HW + pix0 + part * 8] =
            *(const uint4*)&Os[row * 68 + part * 8];
      }
    }
  }
}

// ---------------------------------------------------------------------------
// K2: cape = depthwise5x5(v) + b_cape -> d_out (fp32 NCHW)  (unchanged)
// ---------------------------------------------------------------------------
__global__ __launch_bounds__(256) void k2_cape(
    const unsigned short* __restrict__ v_buf, const float* __restrict__ w_cape,
    const float* __restrict__ b_cape, float* __restrict__ cape_out) {
  const int c = blockIdx.y, b = blockIdx.z;
  const int h = blockIdx.x * 16 + (threadIdx.x >> 4);
  const int w4 = threadIdx.x & 15;
  const unsigned short* vp = v_buf + ((size_t)b * DIM + c) * HW;
  float wk[25];
#pragma unroll
  for (int i = 0; i < 25; ++i) wk[i] = w_cape[c * 25 + i];
  float acc[4];
  float bz = b_cape[c];
  acc[0] = acc[1] = acc[2] = acc[3] = bz;
#pragma unroll
  for (int dy = 0; dy < 5; ++dy) {
    int hr = h + dy - 2;
    float row[8];
    if (hr >= 0 && hr < RES) {
      const unsigned short* rp = vp + hr * RES + w4 * 4 - 2;
#pragma unroll
      for (int j = 0; j < 4; ++j) {
        int wc = w4 * 4 - 2 + 2 * j;
        unsigned int d = (wc >= 0 && wc < RES) ? *(const unsigned int*)(rp + 2 * j) : 0u;
        row[2 * j] = bf2f((unsigned short)(d & 0xffff));
        row[2 * j + 1] = bf2f((unsigned short)(d >> 16));
      }
    } else {
#pragma unroll
      for (int j = 0; j < 8; ++j) row[j] = 0.f;
    }
#pragma unroll
    for (int wj = 0; wj < 4; ++wj)
#pragma unroll
      for (int dx = 0; dx < 5; ++dx) acc[wj] += row[wj + dx] * wk[dy * 5 + dx];
  }
  float4 o;
  o.x = acc[0]; o.y = acc[1]; o.z = acc[2]; o.w = acc[3];
  *(float4*)&cape_out[((size_t)b * DIM + c) * HW + h * RES + w4 * 4] = o;
}

// ---------------------------------------------------------------------------
// K3/K4: qf/kf = (depthwise5x5(raw) + bias + cape) * scale -> windowed [wi][l][c]
// (unchanged; qf's scale folds log2e for k5's exp2-domain softmax)
// ---------------------------------------------------------------------------
__global__ __launch_bounds__(256) void k3_dw(
    const unsigned short* __restrict__ src, const float* __restrict__ w5,
    const float* __restrict__ b5, const float* __restrict__ cape,
    unsigned short* __restrict__ dst_w, float scale) {
  __shared__ unsigned short patch[64 * 168];  // [c][20 rows x 8 cols]
  __shared__ unsigned short outS[64 * 72];    // [l_local][c], stride 72
  const int lid = blockIdx.x;  // 6144, XCD-swizzled
  const int xx = lid & 7;
  const int ii = lid >> 3;            // 0..767
  const int b = xx * 4 + ii / 192;    // all blocks of b share XCD xx
  const int rem = ii % 192;
  const int wb = rem / 12;
  const int rr2 = rem % 12;
  const int ct = rr2 >> 2, ht = rr2 & 3;
  const int c0 = ct * 64, h0 = ht * 16;
  const int tid = threadIdx.x;

  for (int it = 0; it < 5; ++it) {
    int u = it * 256 + tid;  // < 1280
    int c = u / 20, rr = u % 20;
    int hr = h0 - 2 + rr;
    uint4 pk;
    pk.x = pk.y = pk.z = pk.w = 0u;
    if (hr >= 0 && hr < RES) {
      const unsigned short* rp =
          src + ((size_t)b * DIM + c0 + c) * HW + hr * RES + wb * 4 - 2;
      unsigned int dw[4];
#pragma unroll
      for (int j = 0; j < 4; ++j) {
        int wc = wb * 4 - 2 + 2 * j;
        dw[j] = (wc >= 0 && wc < RES) ? *(const unsigned int*)(rp + 2 * j) : 0u;
      }
      pk.x = dw[0]; pk.y = dw[1]; pk.z = dw[2]; pk.w = dw[3];
    }
    *(uint4*)&patch[c * 168 + rr * 8] = pk;
  }
  __syncthreads();

  const int c = tid >> 2, hq = tid & 3;
  float wk[25];
#pragma unroll
  for (int i = 0; i < 25; ++i) wk[i] = w5[(c0 + c) * 25 + i];
  float bz = b5[c0 + c];
  float acc[4][4];
#pragma unroll
  for (int j = 0; j < 4; ++j)
#pragma unroll
    for (int wm = 0; wm < 4; ++wm) acc[j][wm] = bz;

#pragma unroll
  for (int rel = 0; rel < 8; ++rel) {
    int p = hq * 4 + rel;
    uint4 pk = *(const uint4*)&patch[c * 168 + p * 8];
    float f8[8];
    f8[0] = bf2f((unsigned short)(pk.x & 0xffff));
    f8[1] = bf2f((unsigned short)(pk.x >> 16));
    f8[2] = bf2f((unsigned short)(pk.y & 0xffff));
    f8[3] = bf2f((unsigned short)(pk.y >> 16));
    f8[4] = bf2f((unsigned short)(pk.z & 0xffff));
    f8[5] = bf2f((unsigned short)(pk.z >> 16));
    f8[6] = bf2f((unsigned short)(pk.w & 0xffff));
    f8[7] = bf2f((unsigned short)(pk.w >> 16));
#pragma unroll
    for (int j = 0; j < 4; ++j) {
      int dy = rel - j;
      if (dy >= 0 && dy <= 4) {
#pragma unroll
        for (int wm = 0; wm < 4; ++wm)
#pragma unroll
          for (int dx = 0; dx < 5; ++dx) acc[j][wm] += f8[wm + dx] * wk[dy * 5 + dx];
      }
    }
  }

  size_t cpbase = ((size_t)b * DIM + c0 + c) * HW + (size_t)wb * 4;
#pragma unroll
  for (int j = 0; j < 4; ++j) {
    int h = h0 + hq * 4 + j;
    float4 cp = *(const float4*)&cape[cpbase + (size_t)h * RES];
    int lb = (hq * 4 + j) * 4;  // l_local base
    outS[(lb + 0) * 72 + c] = f2bf((acc[j][0] + cp.x) * scale);
    outS[(lb + 1) * 72 + c] = f2bf((acc[j][1] + cp.y) * scale);
    outS[(lb + 2) * 72 + c] = f2bf((acc[j][2] + cp.z) * scale);
    outS[(lb + 3) * 72 + c] = f2bf((acc[j][3] + cp.w) * scale);
  }
  __syncthreads();

  // cooperative coalesced store: 64 l_local rows x 64 c
  const size_t obase = ((size_t)(b * NWIN + wb) * LTOK + (size_t)h0 * 4) * DIM + c0;
  for (int it = 0; it < 2; ++it) {
    int u = it * 256 + tid;  // < 512
    int ll = u >> 3, part = u & 7;
    *(uint4*)&dst_w[obase + (size_t)ll * DIM + part * 8] =
        *(const uint4*)&outS[ll * 72 + part * 8];
  }
}

// ---------------------------------------------------------------------------
// K5: windowed attention.  r8: (a) revert asm cvt_pk -> f2bf pack (m240:
// hand-written cvt_pk asm hurts); (b) all 64 PV bpermutes issued as ONE
// burst (static-unrolled pe/po arrays) so the LDS pipe streams with rolling
// waits instead of 8 per-ksi lgkmcnt(0) drains; (c) s_setprio(1) around the
// QK and PV MFMA clusters (T5).  Structure from r6/r7 otherwise unchanged.
// ---------------------------------------------------------------------------
#define KSTR 56
#define VSTR 256

__global__ __launch_bounds__(256, 3) void k5_attn(
    const unsigned short* __restrict__ qf_w, const unsigned short* __restrict__ kf_w,
    const unsigned short* __restrict__ v_buf, unsigned short* __restrict__ out_w) {
  __shared__ unsigned short smem[26624];  // 53248 B
  unsigned short* Kl = smem;              // [256][56] = 28672 B
  unsigned short* Vl = smem + 14336;      // [48][256] = 24576 B, xor-swizzled

  const int lid = blockIdx.x;  // 2048, XCD-swizzled: all blocks of b on XCD lid&7
  const int xx = lid & 7;
  const int ii = lid >> 3;              // 0..255
  const int b = (xx << 2) | (ii >> 6);  // 0..31
  const int rem = ii & 63;
  const int wb = rem >> 2;
  const int hd = rem & 3;
  const int wi = b * NWIN + wb;

  const int tid = threadIdx.x, lane = tid & 63, wv = tid >> 6;
  const int quad = lane >> 4, col = lane & 15;
  // wave wv owns q rows [wv*64, wv*64+64), in 4 passes of 16 (nt)

  short8 z8 = {0, 0, 0, 0, 0, 0, 0, 0};
  const unsigned short* qbase =
      qf_w + ((size_t)wi * LTOK + wv * 64 + col) * DIM + hd * DH;

  // Q fragments for pass 0, issued before staging to hide latency
  short8 bq0 = *(const short8*)(qbase + quad * 8);
  short8 bq1 = z8;
  if (quad < 2) bq1 = *(const short8*)(qbase + 32 + quad * 8);

  // stage K [kl][d] stride 56
  {
    const unsigned short* ks = kf_w + (size_t)wi * LTOK * DIM + hd * DH;
    for (int it = 0; it < 6; ++it) {
      int u = it * 256 + tid;
      int kl = u / 6, part = u % 6;
      *(uint4*)&Kl[kl * KSTR + part * 8] = *(const uint4*)(ks + (size_t)kl * DIM + part * 8);
    }
  }
  // stage V^T [d][kl] xor-swizzled (kl8 ^= d&7)
  {
    const unsigned short* vs = v_buf + ((size_t)b * DIM + hd * DH) * HW + wb * 4;
    for (int it = 0; it < 12; ++it) {
      int u = it * 256 + tid;
      int d = u >> 6, h = u & 63;
      int kl8 = h >> 1;
      int off = ((kl8 ^ (d & 7)) * 8) + (h & 1) * 4;
      *(uint2*)&Vl[d * VSTR + off] = *(const uint2*)(vs + (size_t)d * HW + h * RES);
    }
  }
  __syncthreads();  // the only barrier in this kernel

  const int aA = (32 * (quad & 1) + col) * 4;
  const int aB = aA + 64;
  const bool lowq = quad < 2;

#pragma unroll
  for (int nt = 0; nt < 4; ++nt) {
    // ---- S^T = K Q^T : a = K rows (m=kl), b = Q rows (n = this pass's 16 q)
    f32x4 s[16];
#pragma unroll
    for (int i = 0; i < 16; ++i) { s[i][0] = 0.f; s[i][1] = 0.f; s[i][2] = 0.f; s[i][3] = 0.f; }
    __builtin_amdgcn_s_setprio(1);
#pragma unroll
    for (int fm = 0; fm < 16; ++fm) {
      short8 a0 = *(const short8*)&Kl[(fm * 16 + col) * KSTR + quad * 8];
      s[fm] = mfma16(a0, bq0, s[fm]);
    }
#pragma unroll
    for (int fm = 0; fm < 16; ++fm) {
      short8 a1 = z8;
      if (quad < 2) a1 = *(const short8*)&Kl[(fm * 16 + col) * KSTR + 32 + quad * 8];
      s[fm] = mfma16(a1, bq1, s[fm]);
    }
    __builtin_amdgcn_s_setprio(0);

    // prefetch next pass's Q while softmax/PV run
    short8 nq0 = z8, nq1 = z8;
    if (nt < 3) {
      const unsigned short* qn = qbase + (size_t)(nt + 1) * 16 * DIM;
      nq0 = *(const short8*)(qn + quad * 8);
      if (quad < 2) nq1 = *(const short8*)(qn + 32 + quad * 8);
    }

    // ---- softmax (exp2 domain): row q lives in lanes {col,+16,+32,+48}
    // tree max (dep depth ~7 instead of 64)
    float m4[16];
#pragma unroll
    for (int fm = 0; fm < 16; ++fm)
      m4[fm] = fmaxf(fmaxf(s[fm][0], s[fm][1]), fmaxf(s[fm][2], s[fm][3]));
#pragma unroll
    for (int i = 0; i < 8; ++i) m4[i] = fmaxf(m4[i], m4[i + 8]);
#pragma unroll
    for (int i = 0; i < 4; ++i) m4[i] = fmaxf(m4[i], m4[i + 4]);
    float mx = fmaxf(fmaxf(m4[0], m4[2]), fmaxf(m4[1], m4[3]));
    mx = fmaxf(mx, __shfl_xor(mx, 16));
    mx = fmaxf(mx, __shfl_xor(mx, 32));

    // exp2 + tree sum
    float s4[16];
#pragma unroll
    for (int fm = 0; fm < 16; ++fm) {
      float e0 = __builtin_exp2f(s[fm][0] - mx);
      float e1 = __builtin_exp2f(s[fm][1] - mx);
      float e2 = __builtin_exp2f(s[fm][2] - mx);
      float e3 = __builtin_exp2f(s[fm][3] - mx);
      s[fm][0] = e0; s[fm][1] = e1; s[fm][2] = e2; s[fm][3] = e3;
      s4[fm] = (e0 + e1) + (e2 + e3);
    }
#pragma unroll
    for (int i = 0; i < 8; ++i) s4[i] += s4[i + 8];
#pragma unroll
    for (int i = 0; i < 4; ++i) s4[i] += s4[i + 4];
    float sm = (s4[0] + s4[2]) + (s4[1] + s4[3]);
    sm += __shfl_xor(sm, 16);
    sm += __shfl_xor(sm, 32);
    float inv = __builtin_amdgcn_rcpf(sm);

    // ---- pack RAW e as bf16 pairs (normalization deferred to epilogue)
    unsigned int w0[16], w1[16];
#pragma unroll
    for (int fm = 0; fm < 16; ++fm) {
      w0[fm] = (unsigned int)f2bf(s[fm][0]) | ((unsigned int)f2bf(s[fm][1]) << 16);
      w1[fm] = (unsigned int)f2bf(s[fm][2]) | ((unsigned int)f2bf(s[fm][3]) << 16);
    }

    // inv for output rows quad*4+r (uniform across quads at lane col=q)
    float ivr[4];
#pragma unroll
    for (int r = 0; r < 4; ++r)
      ivr[r] = __builtin_bit_cast(
          float, __builtin_amdgcn_ds_bpermute((quad * 4 + r) * 4,
                                              __builtin_bit_cast(int, inv)));

    // ---- batched bpermute burst: all 64 issued before any consumption,
    // so the LDS pipe streams (no per-ksi lgkmcnt(0) drain stalls).
    int pe[32], po[32];
#pragma unroll
    for (int ksi = 0; ksi < 8; ++ksi) {
      const int fe = 2 * ksi, fo = 2 * ksi + 1;
      pe[ksi * 4 + 0] = __builtin_amdgcn_ds_bpermute(aA, (int)w0[fe]);
      po[ksi * 4 + 0] = __builtin_amdgcn_ds_bpermute(aA, (int)w0[fo]);
      pe[ksi * 4 + 1] = __builtin_amdgcn_ds_bpermute(aA, (int)w1[fe]);
      po[ksi * 4 + 1] = __builtin_amdgcn_ds_bpermute(aA, (int)w1[fo]);
      pe[ksi * 4 + 2] = __builtin_amdgcn_ds_bpermute(aB, (int)w0[fe]);
      po[ksi * 4 + 2] = __builtin_amdgcn_ds_bpermute(aB, (int)w0[fo]);
      pe[ksi * 4 + 3] = __builtin_amdgcn_ds_bpermute(aB, (int)w1[fe]);
      po[ksi * 4 + 3] = __builtin_amdgcn_ds_bpermute(aB, (int)w1[fo]);
    }

    // ---- O = P V
    f32x4 o[3];
#pragma unroll
    for (int i = 0; i < 3; ++i) { o[i][0] = 0.f; o[i][1] = 0.f; o[i][2] = 0.f; o[i][3] = 0.f; }
    __builtin_amdgcn_s_setprio(1);
#pragma unroll
    for (int ksi = 0; ksi < 8; ++ksi) {
      i32x4 aw;
      aw[0] = lowq ? pe[ksi * 4 + 0] : po[ksi * 4 + 0];
      aw[1] = lowq ? pe[ksi * 4 + 1] : po[ksi * 4 + 1];
      aw[2] = lowq ? pe[ksi * 4 + 2] : po[ksi * 4 + 2];
      aw[3] = lowq ? pe[ksi * 4 + 3] : po[ksi * 4 + 3];
      short8 a = __builtin_bit_cast(short8, aw);
#pragma unroll
      for (int fn = 0; fn < 3; ++fn) {
        int d = fn * 16 + col;
        short8 bb = *(const short8*)&Vl[d * VSTR + (((ksi * 4 + quad) ^ (d & 7)) * 8)];
        o[fn] = mfma16(a, bb, o[fn]);
      }
    }
    __builtin_amdgcn_s_setprio(0);

    // ---- direct epilogue with deferred normalization
    {
      unsigned short* dst =
          out_w + ((size_t)wi * LTOK + wv * 64 + nt * 16) * DIM + hd * DH;
#pragma unroll
      for (int fn = 0; fn < 3; ++fn)
#pragma unroll
        for (int r = 0; r < 4; ++r)
          dst[(size_t)(quad * 4 + r) * DIM + fn * 16 + col] = f2bf(o[fn][r] * ivr[r]);
    }

    bq0 = nq0;
    bq1 = nq1;
  }
}

// ---------------------------------------------------------------------------
// K6: windows2img(out_w) + cape -> d_out (unchanged)
// ---------------------------------------------------------------------------
__global__ __launch_bounds__(256) void k6_final(
    const unsigned short* __restrict__ out_w, float* __restrict__ io) {
  __shared__ float tile[16 * 528];  // [c]*528 + [h]*66 + [w]
  const int ht = blockIdx.x, ct = blockIdx.y, b = blockIdx.z;  // grid(8,12,32)
  const int c0 = ct * 16, h0 = ht * 8;
  const int tid = threadIdx.x;
  for (int it = 0; it < 4; ++it) {
    int u = it * 256 + tid;  // < 1024 = 16wb x 32l x 2chunks
    int chunk = u & 1, l5 = (u >> 1) & 31, wb = u >> 6;
    const unsigned short* p =
        out_w + ((size_t)(b * NWIN + wb) * LTOK + (size_t)(h0 * 4 + l5)) * DIM + c0 + chunk * 8;
    uint4 pk = *(const uint4*)p;
    int h = l5 >> 2, wm = l5 & 3;
    float* t = &tile[(chunk * 8) * 528 + h * 66 + wb * 4 + wm];
    t[0 * 528] = bf2f((unsigned short)(pk.x & 0xffff));
    t[1 * 528] = bf2f((unsigned short)(pk.x >> 16));
    t[2 * 528] = bf2f((unsigned short)(pk.y & 0xffff));
    t[3 * 528] = bf2f((unsigned short)(pk.y >> 16));
    t[4 * 528] = bf2f((unsigned short)(pk.z & 0xffff));
    t[5 * 528] = bf2f((unsigned short)(pk.z >> 16));
    t[6 * 528] = bf2f((unsigned short)(pk.w & 0xffff));
    t[7 * 528] = bf2f((unsigned short)(pk.w >> 16));
  }
  __syncthreads();
  for (int it = 0; it < 8; ++it) {
    int u = it * 256 + tid;
    int w16 = u & 15, h = (u >> 4) & 7, c = u >> 7;
    size_t g = ((size_t)b * DIM + c0 + c) * HW + (size_t)(h0 + h) * RES + w16 * 4;
    float4 cp = *(const float4*)&io[g];
    float4 ov;
    ov.x = tile[c * 528 + h * 66 + w16 * 4 + 0] + cp.x;
    ov.y = tile[c * 528 + h * 66 + w16 * 4 + 1] + cp.y;
    ov.z = tile[c * 528 + h * 66 + w16 * 4 + 2] + cp.z;
    ov.w = tile[c * 528 + h * 66 + w16 * 4 + 3] + cp.w;
    *(float4*)&io[g] = ov;
  }
}

// ---------------------------------------------------------------------------
extern "C" void kernel_launch(void* const* d_in, const int* in_sizes, int n_in,
                              void* d_out, int out_size, void* d_ws, size_t ws_size,
                              hipStream_t stream) {
  (void)in_sizes; (void)n_in; (void)out_size; (void)ws_size;
  const float* x = (const float*)d_in[0];
  const float* w_qk = (const float*)d_in[1];
  const float* b_qk = (const float*)d_in[2];
  const float* w_q5 = (const float*)d_in[3];
  const float* b_q5 = (const float*)d_in[4];
  const float* w_k5 = (const float*)d_in[5];
  const float* b_k5 = (const float*)d_in[6];
  const float* w_v = (const float*)d_in[7];
  const float* b_v = (const float*)d_in[8];
  const float* w_cape = (const float*)d_in[9];
  const float* b_cape = (const float*)d_in[10];
  float* out = (float*)d_out;

  unsigned short* ws = (unsigned short*)d_ws;
  unsigned short* buf0 = ws;                     // q_raw, later kf_w
  unsigned short* buf1 = ws + (size_t)BUFE;      // k_raw, later out_w
  unsigned short* buf2 = ws + (size_t)BUFE * 2;  // v (NCHW bf16)
  unsigned short* buf3 = ws + (size_t)BUFE * 3;  // wbf (weights), later qf_w

  k0_wcvt<<<dim3(108), 256, 0, stream>>>(w_qk, w_v, buf3);
  k1_conv1x1<<<dim3(64, 32), 256, 0, stream>>>(x, buf3, b_qk, b_v, buf0, buf1, buf2);
  k2_cape<<<dim3(4, 192, 32), 256, 0, stream>>>(buf2, w_cape, b_cape, out);
  // qf scale folds log2e so k5's softmax runs in exp2 domain
  k3_dw<<<dim3(6144), 256, 0, stream>>>(buf0, w_q5, b_q5, out, buf3, SCALE_Q * LOG2E);
  k3_dw<<<dim3(6144), 256, 0, stream>>>(buf1, w_k5, b_k5, out, buf0, 1.0f);
  k5_attn<<<dim3(2048), 256, 0, stream>>>(buf3, buf0, buf2, buf1);
  k6_final<<<dim3(8, 12, 32), 256, 0, stream>>>(buf1, out);
}

// Round 8
// 624.975 us; speedup vs baseline: 1.0584x; 1.0584x over previous
//
#include <hip/hip_runtime.h>

typedef short short8 __attribute__((ext_vector_type(8)));
typedef float f32x4 __attribute__((ext_vector_type(4)));
typedef int i32x4 __attribute__((ext_vector_type(4)));
typedef uint4 uint4_a4 __attribute__((aligned(4)));  // 4B-aligned 16B load
typedef uint2 uint2_a4 __attribute__((aligned(4)));

#define BATCH 32
#define DIM 192
#define RES 64
#define HW 4096
#define NH 4
#define DH 48
#define NWIN 16
#define LTOK 256
#define BUFE (BATCH * DIM * HW)  // 25,165,824 elems per bf16 buffer
#define SCALE_Q 0.14433756729740643f
#define LOG2E 1.4426950408889634f

__device__ __forceinline__ unsigned short f2bf(float f) {
  unsigned int u = __builtin_bit_cast(unsigned int, f);
  u += 0x7fffu + ((u >> 16) & 1u);
  return (unsigned short)(u >> 16);
}
__device__ __forceinline__ float bf2f(unsigned short h) {
  unsigned int u = ((unsigned int)h) << 16;
  return __builtin_bit_cast(float, u);
}
__device__ __forceinline__ f32x4 mfma16(short8 a, short8 b, f32x4 c) {
  return __builtin_amdgcn_mfma_f32_16x16x32_bf16(a, b, c, 0, 0, 0);
}

// ---------------------------------------------------------------------------
// K0: one-shot weight fp32->bf16 conversion into wbf[576][192] (lives in buf3,
// which is dead until k3 writes qf_w there).
// ---------------------------------------------------------------------------
__global__ __launch_bounds__(256) void k0_wcvt(
    const float* __restrict__ w_qk, const float* __restrict__ w_v,
    unsigned short* __restrict__ wbf) {
  int u = blockIdx.x * 256 + threadIdx.x;  // 0..27647
  int i4 = u * 4;
  const float* src = (i4 < 2 * DIM * DIM) ? (w_qk + i4) : (w_v + (i4 - 2 * DIM * DIM));
  float4 f = *(const float4*)src;
  uint2 pk;
  pk.x = (unsigned int)f2bf(f.x) | ((unsigned int)f2bf(f.y) << 16);
  pk.y = (unsigned int)f2bf(f.z) | ((unsigned int)f2bf(f.w) << 16);
  *(uint2*)&wbf[i4] = pk;
}

// ---------------------------------------------------------------------------
// K1: 1x1 convs as bf16 MFMA GEMM (unchanged from r4).
// ---------------------------------------------------------------------------
__global__ __launch_bounds__(256, 2) void k1_conv1x1(
    const float* __restrict__ x, const unsigned short* __restrict__ wbf,
    const float* __restrict__ b_qk, const float* __restrict__ b_v,
    unsigned short* __restrict__ q_raw, unsigned short* __restrict__ k_raw,
    unsigned short* __restrict__ v_buf) {
  __shared__ unsigned short Al[96 * 200];  // weight tile, stride 200
  __shared__ unsigned short Bl[64 * 200];  // x tile [px][ic], stride 200
  __shared__ unsigned short Os[96 * 68];   // output tile [oc][px], stride 68
  const int tid = threadIdx.x;
  const int pix0 = blockIdx.x * 64;
  const int b = blockIdx.y;

  // stage B (x tile) once: [px][ic] stride 200
  {
    const float* xb = x + (size_t)b * (DIM * HW) + pix0;
    int px = tid & 63;
    int icq = tid >> 6;
    for (int it = 0; it < 6; ++it) {
      int ic8 = icq + it * 4;
      const float* p = xb + (size_t)(ic8 * 8) * HW + px;
      unsigned short h[8];
#pragma unroll
      for (int j = 0; j < 8; ++j) h[j] = f2bf(p[(size_t)j * HW]);
      uint4 pk;
      pk.x = h[0] | ((unsigned int)h[1] << 16);
      pk.y = h[2] | ((unsigned int)h[3] << 16);
      pk.z = h[4] | ((unsigned int)h[5] << 16);
      pk.w = h[6] | ((unsigned int)h[7] << 16);
      *(uint4*)&Bl[px * 200 + ic8 * 8] = pk;
    }
  }

  const int lane = tid & 63, wv = tid >> 6;
  const int quad = lane >> 4, col = lane & 15;
  const int m0 = (wv >> 1) * 48, n0 = (wv & 1) * 32;

  for (int t = 0; t < 6; ++t) {
    // stage weight tile t: global(L2-resident) -> LDS, short-lived regs only
    {
      const unsigned short* wsrc = wbf + t * (96 * 192);
      uint4 tmp[9];
#pragma unroll
      for (int it = 0; it < 9; ++it) {
        int row = (it * 256 + tid) / 24, part = (it * 256 + tid) % 24;
        tmp[it] = *(const uint4*)(wsrc + row * 192 + part * 8);
      }
#pragma unroll
      for (int it = 0; it < 9; ++it) {
        int row = (it * 256 + tid) / 24, part = (it * 256 + tid) % 24;
        *(uint4*)&Al[row * 200 + part * 8] = tmp[it];
      }
    }
    __syncthreads();  // Al ready (t=0 also covers Bl staging)

    f32x4 acc[3][2];
#pragma unroll
    for (int fm = 0; fm < 3; ++fm)
#pragma unroll
      for (int fn = 0; fn < 2; ++fn) {
        acc[fm][fn][0] = 0.f; acc[fm][fn][1] = 0.f;
        acc[fm][fn][2] = 0.f; acc[fm][fn][3] = 0.f;
      }

#pragma unroll
    for (int ks = 0; ks < 6; ++ks) {
      short8 a[3], bb[2];
#pragma unroll
      for (int fm = 0; fm < 3; ++fm)
        a[fm] = *(const short8*)&Al[(m0 + fm * 16 + col) * 200 + ks * 32 + quad * 8];
#pragma unroll
      for (int fn = 0; fn < 2; ++fn)
        bb[fn] = *(const short8*)&Bl[(n0 + fn * 16 + col) * 200 + ks * 32 + quad * 8];
#pragma unroll
      for (int fm = 0; fm < 3; ++fm)
#pragma unroll
        for (int fn = 0; fn < 2; ++fn) acc[fm][fn] = mfma16(a[fm], bb[fn], acc[fm][fn]);
    }

    // write O tile (bias added, bf16) into Os [96 rows][stride 68]
    const int oc0 = t * 96;
#pragma unroll
    for (int fm = 0; fm < 3; ++fm) {
#pragma unroll
      for (int r = 0; r < 4; ++r) {
        int ocoff = m0 + fm * 16 + quad * 4 + r;
        int ocg = oc0 + ocoff;
        float bias = (ocg < 384) ? b_qk[ocg] : b_v[ocg - 384];
#pragma unroll
        for (int fn = 0; fn < 2; ++fn) {
          int px = n0 + fn * 16 + col;
          Os[ocoff * 68 + px] = f2bf(acc[fm][fn][r] + bias);
        }
      }
    }
    __syncthreads();  // Os ready; doubles as "all Al reads done" fence

    // cooperative full-line store: 8 lanes = one 128-B row line
    unsigned short* dst;
    int ocbase;
    if (oc0 < 192) { dst = q_raw; ocbase = oc0; }
    else if (oc0 < 384) { dst = k_raw; ocbase = oc0 - 192; }
    else { dst = v_buf; ocbase = oc0 - 384; }
    {
      int row0 = tid >> 3, part = tid & 7;
#pragma unroll
      for (int it = 0; it < 3; ++it) {
        int row = it * 32 + row0;
        *(uint4*)&dst[((size_t)b * DIM + (ocbase + row)) * HW + pix0 + part * 8] =
            *(const uint4*)&Os[row * 68 + part * 8];
      }
    }
  }
}

// ---------------------------------------------------------------------------
// K2: cape = depthwise5x5(v) + b_cape -> d_out (fp32 NCHW).
// r9: row loads 4x4B -> single 16B uint4 (4B-aligned) with register masking
// at the w edges — 4x fewer memory requests.
// ---------------------------------------------------------------------------
__global__ __launch_bounds__(256) void k2_cape(
    const unsigned short* __restrict__ v_buf, const float* __restrict__ w_cape,
    const float* __restrict__ b_cape, float* __restrict__ cape_out) {
  const int c = blockIdx.y, b = blockIdx.z;
  const int h = blockIdx.x * 16 + (threadIdx.x >> 4);
  const int w4 = threadIdx.x & 15;
  const unsigned short* vp = v_buf + ((size_t)b * DIM + c) * HW;
  float wk[25];
#pragma unroll
  for (int i = 0; i < 25; ++i) wk[i] = w_cape[c * 25 + i];
  float acc[4];
  float bz = b_cape[c];
  acc[0] = acc[1] = acc[2] = acc[3] = bz;
#pragma unroll
  for (int dy = 0; dy < 5; ++dy) {
    int hr = h + dy - 2;
    float row[8];
    if (hr >= 0 && hr < RES) {
      const unsigned short* rp = vp + hr * RES + w4 * 4 - 2;
      uint4 pk;
      pk.x = pk.y = pk.z = pk.w = 0u;
      if (w4 == 0) {
        uint2_a4 m = *(const uint2_a4*)(rp + 2);  // w0..3 (8B-aligned)
        pk.y = m.x; pk.z = m.y;
        pk.w = *(const unsigned int*)(rp + 6);    // w4,5
      } else if (w4 == 15) {
        pk.x = *(const unsigned int*)rp;          // w58,59
        uint2_a4 m = *(const uint2_a4*)(rp + 2);  // w60..63
        pk.y = m.x; pk.z = m.y;
      } else {
        pk = *(const uint4_a4*)rp;                // 4B-aligned 16B
      }
      row[0] = bf2f((unsigned short)(pk.x & 0xffff));
      row[1] = bf2f((unsigned short)(pk.x >> 16));
      row[2] = bf2f((unsigned short)(pk.y & 0xffff));
      row[3] = bf2f((unsigned short)(pk.y >> 16));
      row[4] = bf2f((unsigned short)(pk.z & 0xffff));
      row[5] = bf2f((unsigned short)(pk.z >> 16));
      row[6] = bf2f((unsigned short)(pk.w & 0xffff));
      row[7] = bf2f((unsigned short)(pk.w >> 16));
    } else {
#pragma unroll
      for (int j = 0; j < 8; ++j) row[j] = 0.f;
    }
#pragma unroll
    for (int wj = 0; wj < 4; ++wj)
#pragma unroll
      for (int dx = 0; dx < 5; ++dx) acc[wj] += row[wj + dx] * wk[dy * 5 + dx];
  }
  float4 o;
  o.x = acc[0]; o.y = acc[1]; o.z = acc[2]; o.w = acc[3];
  *(float4*)&cape_out[((size_t)b * DIM + c) * HW + h * RES + w4 * 4] = o;
}

// ---------------------------------------------------------------------------
// K3/K4: qf/kf = (depthwise5x5(raw) + bias + cape) * scale -> windowed [wi][l][c]
// r9: (a) staging 20x4B loads -> 5x16B uint4 (uniform per-block edge variants,
// register zero-mask) — ~4x fewer memory requests; (b) cape float4s + weights
// prefetched BEFORE staging so their latency hides under staging+conv.
// ---------------------------------------------------------------------------
__global__ __launch_bounds__(256) void k3_dw(
    const unsigned short* __restrict__ src, const float* __restrict__ w5,
    const float* __restrict__ b5, const float* __restrict__ cape,
    unsigned short* __restrict__ dst_w, float scale) {
  __shared__ unsigned short patch[64 * 168];  // [c][20 rows x 8 cols]
  __shared__ unsigned short outS[64 * 72];    // [l_local][c], stride 72
  const int lid = blockIdx.x;  // 6144, XCD-swizzled
  const int xx = lid & 7;
  const int ii = lid >> 3;            // 0..767
  const int b = xx * 4 + ii / 192;    // all blocks of b share XCD xx
  const int rem = ii % 192;
  const int wb = rem / 12;
  const int rr2 = rem % 12;
  const int ct = rr2 >> 2, ht = rr2 & 3;
  const int c0 = ct * 64, h0 = ht * 16;
  const int tid = threadIdx.x;

  // ---- early issue: weights, bias, cape (latency overlaps staging + conv)
  const int c = tid >> 2, hq = tid & 3;
  float wk[25];
#pragma unroll
  for (int i = 0; i < 25; ++i) wk[i] = w5[(c0 + c) * 25 + i];
  float bz = b5[c0 + c];
  const size_t cpbase = ((size_t)b * DIM + c0 + c) * HW + (size_t)wb * 4;
  float4 cp4[4];
#pragma unroll
  for (int j = 0; j < 4; ++j)
    cp4[j] = *(const float4*)&cape[cpbase + (size_t)(h0 + hq * 4 + j) * RES];

  // ---- staging: one 16B (or edge 2-load) read per (c,row)
  for (int it = 0; it < 5; ++it) {
    int u = it * 256 + tid;  // < 1280
    int cc = u / 20, rr = u % 20;
    int hr = h0 - 2 + rr;
    uint4 pk;
    pk.x = pk.y = pk.z = pk.w = 0u;
    if (hr >= 0 && hr < RES) {
      const unsigned short* rp =
          src + ((size_t)b * DIM + c0 + cc) * HW + hr * RES + wb * 4 - 2;
      if (wb == 0) {
        uint2_a4 m = *(const uint2_a4*)(rp + 2);  // w0..3
        pk.y = m.x; pk.z = m.y;
        pk.w = *(const unsigned int*)(rp + 6);    // w4,5
      } else if (wb == 15) {
        pk.x = *(const unsigned int*)rp;          // w58,59
        uint2_a4 m = *(const uint2_a4*)(rp + 2);  // w60..63
        pk.y = m.x; pk.z = m.y;
      } else {
        pk = *(const uint4_a4*)rp;                // 4B-aligned 16B
      }
    }
    *(uint4*)&patch[cc * 168 + rr * 8] = pk;
  }
  __syncthreads();

  float acc[4][4];
#pragma unroll
  for (int j = 0; j < 4; ++j)
#pragma unroll
    for (int wm = 0; wm < 4; ++wm) acc[j][wm] = bz;

#pragma unroll
  for (int rel = 0; rel < 8; ++rel) {
    int p = hq * 4 + rel;
    uint4 pk = *(const uint4*)&patch[c * 168 + p * 8];
    float f8[8];
    f8[0] = bf2f((unsigned short)(pk.x & 0xffff));
    f8[1] = bf2f((unsigned short)(pk.x >> 16));
    f8[2] = bf2f((unsigned short)(pk.y & 0xffff));
    f8[3] = bf2f((unsigned short)(pk.y >> 16));
    f8[4] = bf2f((unsigned short)(pk.z & 0xffff));
    f8[5] = bf2f((unsigned short)(pk.z >> 16));
    f8[6] = bf2f((unsigned short)(pk.w & 0xffff));
    f8[7] = bf2f((unsigned short)(pk.w >> 16));
#pragma unroll
    for (int j = 0; j < 4; ++j) {
      int dy = rel - j;
      if (dy >= 0 && dy <= 4) {
#pragma unroll
        for (int wm = 0; wm < 4; ++wm)
#pragma unroll
          for (int dx = 0; dx < 5; ++dx) acc[j][wm] += f8[wm + dx] * wk[dy * 5 + dx];
      }
    }
  }

#pragma unroll
  for (int j = 0; j < 4; ++j) {
    float4 cp = cp4[j];
    int lb = (hq * 4 + j) * 4;  // l_local base
    outS[(lb + 0) * 72 + c] = f2bf((acc[j][0] + cp.x) * scale);
    outS[(lb + 1) * 72 + c] = f2bf((acc[j][1] + cp.y) * scale);
    outS[(lb + 2) * 72 + c] = f2bf((acc[j][2] + cp.z) * scale);
    outS[(lb + 3) * 72 + c] = f2bf((acc[j][3] + cp.w) * scale);
  }
  __syncthreads();

  // cooperative coalesced store: 64 l_local rows x 64 c
  const size_t obase = ((size_t)(b * NWIN + wb) * LTOK + (size_t)h0 * 4) * DIM + c0;
  for (int it = 0; it < 2; ++it) {
    int u = it * 256 + tid;  // < 512
    int ll = u >> 3, part = u & 7;
    *(uint4*)&dst_w[obase + (size_t)ll * DIM + part * 8] =
        *(const uint4*)&outS[ll * 72 + part * 8];
  }
}

// ---------------------------------------------------------------------------
// K5: windowed attention (unchanged from r8: batched bpermute burst,
// setprio around MFMA clusters, f2bf pack, deferred normalization).
// ---------------------------------------------------------------------------
#define KSTR 56
#define VSTR 256

__global__ __launch_bounds__(256, 3) void k5_attn(
    const unsigned short* __restrict__ qf_w, const unsigned short* __restrict__ kf_w,
    const unsigned short* __restrict__ v_buf, unsigned short* __restrict__ out_w) {
  __shared__ unsigned short smem[26624];  // 53248 B
  unsigned short* Kl = smem;              // [256][56] = 28672 B
  unsigned short* Vl = smem + 14336;      // [48][256] = 24576 B, xor-swizzled

  const int lid = blockIdx.x;  // 2048, XCD-swizzled: all blocks of b on XCD lid&7
  const int xx = lid & 7;
  const int ii = lid >> 3;              // 0..255
  const int b = (xx << 2) | (ii >> 6);  // 0..31
  const int rem = ii & 63;
  const int wb = rem >> 2;
  const int hd = rem & 3;
  const int wi = b * NWIN + wb;

  const int tid = threadIdx.x, lane = tid & 63, wv = tid >> 6;
  const int quad = lane >> 4, col = lane & 15;

  short8 z8 = {0, 0, 0, 0, 0, 0, 0, 0};
  const unsigned short* qbase =
      qf_w + ((size_t)wi * LTOK + wv * 64 + col) * DIM + hd * DH;

  short8 bq0 = *(const short8*)(qbase + quad * 8);
  short8 bq1 = z8;
  if (quad < 2) bq1 = *(const short8*)(qbase + 32 + quad * 8);

  // stage K [kl][d] stride 56
  {
    const unsigned short* ks = kf_w + (size_t)wi * LTOK * DIM + hd * DH;
    for (int it = 0; it < 6; ++it) {
      int u = it * 256 + tid;
      int kl = u / 6, part = u % 6;
      *(uint4*)&Kl[kl * KSTR + part * 8] = *(const uint4*)(ks + (size_t)kl * DIM + part * 8);
    }
  }
  // stage V^T [d][kl] xor-swizzled (kl8 ^= d&7)
  {
    const unsigned short* vs = v_buf + ((size_t)b * DIM + hd * DH) * HW + wb * 4;
    for (int it = 0; it < 12; ++it) {
      int u = it * 256 + tid;
      int d = u >> 6, h = u & 63;
      int kl8 = h >> 1;
      int off = ((kl8 ^ (d & 7)) * 8) + (h & 1) * 4;
      *(uint2*)&Vl[d * VSTR + off] = *(const uint2*)(vs + (size_t)d * HW + h * RES);
    }
  }
  __syncthreads();  // the only barrier in this kernel

  const int aA = (32 * (quad & 1) + col) * 4;
  const int aB = aA + 64;
  const bool lowq = quad < 2;

#pragma unroll
  for (int nt = 0; nt < 4; ++nt) {
    f32x4 s[16];
#pragma unroll
    for (int i = 0; i < 16; ++i) { s[i][0] = 0.f; s[i][1] = 0.f; s[i][2] = 0.f; s[i][3] = 0.f; }
    __builtin_amdgcn_s_setprio(1);
#pragma unroll
    for (int fm = 0; fm < 16; ++fm) {
      short8 a0 = *(const short8*)&Kl[(fm * 16 + col) * KSTR + quad * 8];
      s[fm] = mfma16(a0, bq0, s[fm]);
    }
#pragma unroll
    for (int fm = 0; fm < 16; ++fm) {
      short8 a1 = z8;
      if (quad < 2) a1 = *(const short8*)&Kl[(fm * 16 + col) * KSTR + 32 + quad * 8];
      s[fm] = mfma16(a1, bq1, s[fm]);
    }
    __builtin_amdgcn_s_setprio(0);

    short8 nq0 = z8, nq1 = z8;
    if (nt < 3) {
      const unsigned short* qn = qbase + (size_t)(nt + 1) * 16 * DIM;
      nq0 = *(const short8*)(qn + quad * 8);
      if (quad < 2) nq1 = *(const short8*)(qn + 32 + quad * 8);
    }

    float m4[16];
#pragma unroll
    for (int fm = 0; fm < 16; ++fm)
      m4[fm] = fmaxf(fmaxf(s[fm][0], s[fm][1]), fmaxf(s[fm][2], s[fm][3]));
#pragma unroll
    for (int i = 0; i < 8; ++i) m4[i] = fmaxf(m4[i], m4[i + 8]);
#pragma unroll
    for (int i = 0; i < 4; ++i) m4[i] = fmaxf(m4[i], m4[i + 4]);
    float mx = fmaxf(fmaxf(m4[0], m4[2]), fmaxf(m4[1], m4[3]));
    mx = fmaxf(mx, __shfl_xor(mx, 16));
    mx = fmaxf(mx, __shfl_xor(mx, 32));

    float s4[16];
#pragma unroll
    for (int fm = 0; fm < 16; ++fm) {
      float e0 = __builtin_exp2f(s[fm][0] - mx);
      float e1 = __builtin_exp2f(s[fm][1] - mx);
      float e2 = __builtin_exp2f(s[fm][2] - mx);
      float e3 = __builtin_exp2f(s[fm][3] - mx);
      s[fm][0] = e0; s[fm][1] = e1; s[fm][2] = e2; s[fm][3] = e3;
      s4[fm] = (e0 + e1) + (e2 + e3);
    }
#pragma unroll
    for (int i = 0; i < 8; ++i) s4[i] += s4[i + 8];
#pragma unroll
    for (int i = 0; i < 4; ++i) s4[i] += s4[i + 4];
    float sm = (s4[0] + s4[2]) + (s4[1] + s4[3]);
    sm += __shfl_xor(sm, 16);
    sm += __shfl_xor(sm, 32);
    float inv = __builtin_amdgcn_rcpf(sm);

    unsigned int w0[16], w1[16];
#pragma unroll
    for (int fm = 0; fm < 16; ++fm) {
      w0[fm] = (unsigned int)f2bf(s[fm][0]) | ((unsigned int)f2bf(s[fm][1]) << 16);
      w1[fm] = (unsigned int)f2bf(s[fm][2]) | ((unsigned int)f2bf(s[fm][3]) << 16);
    }

    float ivr[4];
#pragma unroll
    for (int r = 0; r < 4; ++r)
      ivr[r] = __builtin_bit_cast(
          float, __builtin_amdgcn_ds_bpermute((quad * 4 + r) * 4,
                                              __builtin_bit_cast(int, inv)));

    int pe[32], po[32];
#pragma unroll
    for (int ksi = 0; ksi < 8; ++ksi) {
      const int fe = 2 * ksi, fo = 2 * ksi + 1;
      pe[ksi * 4 + 0] = __builtin_amdgcn_ds_bpermute(aA, (int)w0[fe]);
      po[ksi * 4 + 0] = __builtin_amdgcn_ds_bpermute(aA, (int)w0[fo]);
      pe[ksi * 4 + 1] = __builtin_amdgcn_ds_bpermute(aA, (int)w1[fe]);
      po[ksi * 4 + 1] = __builtin_amdgcn_ds_bpermute(aA, (int)w1[fo]);
      pe[ksi * 4 + 2] = __builtin_amdgcn_ds_bpermute(aB, (int)w0[fe]);
      po[ksi * 4 + 2] = __builtin_amdgcn_ds_bpermute(aB, (int)w0[fo]);
      pe[ksi * 4 + 3] = __builtin_amdgcn_ds_bpermute(aB, (int)w1[fe]);
      po[ksi * 4 + 3] = __builtin_amdgcn_ds_bpermute(aB, (int)w1[fo]);
    }

    f32x4 o[3];
#pragma unroll
    for (int i = 0; i < 3; ++i) { o[i][0] = 0.f; o[i][1] = 0.f; o[i][2] = 0.f; o[i][3] = 0.f; }
    __builtin_amdgcn_s_setprio(1);
#pragma unroll
    for (int ksi = 0; ksi < 8; ++ksi) {
      i32x4 aw;
      aw[0] = lowq ? pe[ksi * 4 + 0] : po[ksi * 4 + 0];
      aw[1] = lowq ? pe[ksi * 4 + 1] : po[ksi * 4 + 1];
      aw[2] = lowq ? pe[ksi * 4 + 2] : po[ksi * 4 + 2];
      aw[3] = lowq ? pe[ksi * 4 + 3] : po[ksi * 4 + 3];
      short8 a = __builtin_bit_cast(short8, aw);
#pragma unroll
      for (int fn = 0; fn < 3; ++fn) {
        int d = fn * 16 + col;
        short8 bb = *(const short8*)&Vl[d * VSTR + (((ksi * 4 + quad) ^ (d & 7)) * 8)];
        o[fn] = mfma16(a, bb, o[fn]);
      }
    }
    __builtin_amdgcn_s_setprio(0);

    {
      unsigned short* dst =
          out_w + ((size_t)wi * LTOK + wv * 64 + nt * 16) * DIM + hd * DH;
#pragma unroll
      for (int fn = 0; fn < 3; ++fn)
#pragma unroll
        for (int r = 0; r < 4; ++r)
          dst[(size_t)(quad * 4 + r) * DIM + fn * 16 + col] = f2bf(o[fn][r] * ivr[r]);
    }

    bq0 = nq0;
    bq1 = nq1;
  }
}

// ---------------------------------------------------------------------------
// K6: windows2img(out_w) + cape -> d_out (unchanged)
// ---------------------------------------------------------------------------
__global__ __launch_bounds__(256) void k6_final(
    const unsigned short* __restrict__ out_w, float* __restrict__ io) {
  __shared__ float tile[16 * 528];  // [c]*528 + [h]*66 + [w]
  const int ht = blockIdx.x, ct = blockIdx.y, b = blockIdx.z;  // grid(8,12,32)
  const int c0 = ct * 16, h0 = ht * 8;
  const int tid = threadIdx.x;
  for (int it = 0; it < 4; ++it) {
    int u = it * 256 + tid;  // < 1024 = 16wb x 32l x 2chunks
    int chunk = u & 1, l5 = (u >> 1) & 31, wb = u >> 6;
    const unsigned short* p =
        out_w + ((size_t)(b * NWIN + wb) * LTOK + (size_t)(h0 * 4 + l5)) * DIM + c0 + chunk * 8;
    uint4 pk = *(const uint4*)p;
    int h = l5 >> 2, wm = l5 & 3;
    float* t = &tile[(chunk * 8) * 528 + h * 66 + wb * 4 + wm];
    t[0 * 528] = bf2f((unsigned short)(pk.x & 0xffff));
    t[1 * 528] = bf2f((unsigned short)(pk.x >> 16));
    t[2 * 528] = bf2f((unsigned short)(pk.y & 0xffff));
    t[3 * 528] = bf2f((unsigned short)(pk.y >> 16));
    t[4 * 528] = bf2f((unsigned short)(pk.z & 0xffff));
    t[5 * 528] = bf2f((unsigned short)(pk.z >> 16));
    t[6 * 528] = bf2f((unsigned short)(pk.w & 0xffff));
    t[7 * 528] = bf2f((unsigned short)(pk.w >> 16));
  }
  __syncthreads();
  for (int it = 0; it < 8; ++it) {
    int u = it * 256 + tid;
    int w16 = u & 15, h = (u >> 4) & 7, c = u >> 7;
    size_t g = ((size_t)b * DIM + c0 + c) * HW + (size_t)(h0 + h) * RES + w16 * 4;
    float4 cp = *(const float4*)&io[g];
    float4 ov;
    ov.x = tile[c * 528 + h * 66 + w16 * 4 + 0] + cp.x;
    ov.y = tile[c * 528 + h * 66 + w16 * 4 + 1] + cp.y;
    ov.z = tile[c * 528 + h * 66 + w16 * 4 + 2] + cp.z;
    ov.w = tile[c * 528 + h * 66 + w16 * 4 + 3] + cp.w;
    *(float4*)&io[g] = ov;
  }
}

// ---------------------------------------------------------------------------
extern "C" void kernel_launch(void* const* d_in, const int* in_sizes, int n_in,
                              void* d_out, int out_size, void* d_ws, size_t ws_size,
                              hipStream_t stream) {
  (void)in_sizes; (void)n_in; (void)out_size; (void)ws_size;
  const float* x = (const float*)d_in[0];
  const float* w_qk = (const float*)d_in[1];
  const float* b_qk = (const float*)d_in[2];
  const float* w_q5 = (const float*)d_in[3];
  const float* b_q5 = (const float*)d_in[4];
  const float* w_k5 = (const float*)d_in[5];
  const float* b_k5 = (const float*)d_in[6];
  const float* w_v = (const float*)d_in[7];
  const float* b_v = (const float*)d_in[8];
  const float* w_cape = (const float*)d_in[9];
  const float* b_cape = (const float*)d_in[10];
  float* out = (float*)d_out;

  unsigned short* ws = (unsigned short*)d_ws;
  unsigned short* buf0 = ws;                     // q_raw, later kf_w
  unsigned short* buf1 = ws + (size_t)BUFE;      // k_raw, later out_w
  unsigned short* buf2 = ws + (size_t)BUFE * 2;  // v (NCHW bf16)
  unsigned short* buf3 = ws + (size_t)BUFE * 3;  // wbf (weights), later qf_w

  k0_wcvt<<<dim3(108), 256, 0, stream>>>(w_qk, w_v, buf3);
  k1_conv1x1<<<dim3(64, 32), 256, 0, stream>>>(x, buf3, b_qk, b_v, buf0, buf1, buf2);
  k2_cape<<<dim3(4, 192, 32), 256, 0, stream>>>(buf2, w_cape, b_cape, out);
  // qf scale folds log2e so k5's softmax runs in exp2 domain
  k3_dw<<<dim3(6144), 256, 0, stream>>>(buf0, w_q5, b_q5, out, buf3, SCALE_Q * LOG2E);
  k3_dw<<<dim3(6144), 256, 0, stream>>>(buf1, w_k5, b_k5, out, buf0, 1.0f);
  k5_attn<<<dim3(2048), 256, 0, stream>>>(buf3, buf0, buf2, buf1);
  k6_final<<<dim3(8, 12, 32), 256, 0, stream>>>(buf1, out);
}